// Round 1
// baseline (689.624 us; speedup 1.0000x reference)
//
#include <hip/hip_runtime.h>
#include <hip/hip_bf16.h>
#include <math.h>

// Problem constants
#define NRES 512
#define CS   384
#define CZ   128
#define CH   16
#define NH   12
#define PQN  4
#define PVN  8

static constexpr float WL_F      = 0.57735026918962576f;   // sqrt(1/3)
static constexpr float HALF_WC_F = 0.11785113019775792f;   // 0.5*sqrt(2/(9*4))

// ---------------------------------------------------------------------------
// Kernel 1: projections q_h,k_h,v_h (512x12x16), q_hp/k_hp (rot-applied ->
// qg,kg 512x12x4x3), v_hp (-> vg 512x12x8x3).
// grid (4 e-quarters, 64 i-blocks of 8 rows), 256 threads.
// ---------------------------------------------------------------------------
__global__ __launch_bounds__(256) void k_proj(
    const float* __restrict__ s, const float* __restrict__ rots,
    const float* __restrict__ trans,
    const float* __restrict__ Wq, const float* __restrict__ Wk,
    const float* __restrict__ Wv, const float* __restrict__ Wqp,
    const float* __restrict__ Wkp, const float* __restrict__ Wvp,
    float* __restrict__ qh, float* __restrict__ kh, float* __restrict__ vh,
    float* __restrict__ qg, float* __restrict__ kg, float* __restrict__ vg)
{
    const int tid = threadIdx.x;
    const int bx  = blockIdx.x;          // e-quarter 0..3
    const int i0  = blockIdx.y * 8;
    __shared__ float s_lds[8][CS];       // 12 KB
    __shared__ float hp_lds[8][288];     // 9.2 KB (point projections for rot)

    for (int idx = tid; idx < 8 * CS; idx += 256) {
        int r = idx / CS, c = idx % CS;
        s_lds[r][c] = s[(size_t)(i0 + r) * CS + c];
    }
    __syncthreads();

    const int e0 = bx * 288;
    for (int e = e0 + tid; e < e0 + 288; e += 256) {
        const float* Wsel; int col, width, kind;
        if (e < 192)      { Wsel = Wq;  col = e;       width = 192; kind = 0; }
        else if (e < 384) { Wsel = Wk;  col = e - 192; width = 192; kind = 1; }
        else if (e < 576) { Wsel = Wv;  col = e - 384; width = 192; kind = 2; }
        else if (e < 720) { Wsel = Wqp; col = e - 576; width = 144; kind = 3; }
        else if (e < 864) { Wsel = Wkp; col = e - 720; width = 144; kind = 4; }
        else              { Wsel = Wvp; col = e - 864; width = 288; kind = 5; }

        float acc[8];
        #pragma unroll
        for (int r = 0; r < 8; ++r) acc[r] = 0.f;
        for (int c = 0; c < CS; ++c) {
            float w = Wsel[(size_t)c * width + col];
            #pragma unroll
            for (int r = 0; r < 8; ++r) acc[r] += s_lds[r][c] * w;
        }
        #pragma unroll
        for (int r = 0; r < 8; ++r) {
            int i = i0 + r;
            if (kind == 0)      qh[(size_t)i * 192 + col] = acc[r];
            else if (kind == 1) kh[(size_t)i * 192 + col] = acc[r];
            else if (kind == 2) vh[(size_t)i * 192 + col] = acc[r];
            else if (kind == 3) hp_lds[r][col]       = acc[r];
            else if (kind == 4) hp_lds[r][144 + col] = acc[r];
            else                hp_lds[r][col]       = acc[r];
        }
    }
    __syncthreads();

    if (bx >= 2) {
        // rigid transform: out[x] = sum_y R[x,y]*v[y] + t[x]
        for (int tt = tid; tt < 768; tt += 256) {
            int r = tt / 96, rem = tt % 96;
            int i = i0 + r;
            float R[9], T[3];
            #pragma unroll
            for (int k = 0; k < 9; ++k) R[k] = rots[(size_t)i * 9 + k];
            #pragma unroll
            for (int k = 0; k < 3; ++k) T[k] = trans[(size_t)i * 3 + k];
            const float* src; float* dst;
            if (bx == 2) {
                if (rem < 48) {
                    int h = rem / 4, p = rem % 4;
                    src = &hp_lds[r][h * 12 + p * 3];
                    dst = &qg[(size_t)i * 144 + h * 12 + p * 3];
                } else {
                    int rem2 = rem - 48, h = rem2 / 4, p = rem2 % 4;
                    src = &hp_lds[r][144 + h * 12 + p * 3];
                    dst = &kg[(size_t)i * 144 + h * 12 + p * 3];
                }
            } else {
                int h = rem / 8, p = rem % 8;
                src = &hp_lds[r][h * 24 + p * 3];
                dst = &vg[(size_t)i * 288 + h * 24 + p * 3];
            }
            float v0 = src[0], v1 = src[1], v2 = src[2];
            #pragma unroll
            for (int x = 0; x < 3; ++x)
                dst[x] = R[x * 3 + 0] * v0 + R[x * 3 + 1] * v1 + R[x * 3 + 2] * v2 + T[x];
        }
    }
}

// ---------------------------------------------------------------------------
// Kernel 2: per-query-i attention. grid 512, block 256.
// Phase A: logits[j][h] for all j,h into LDS (b_ij from z, q.k, dist2).
// Phase B: softmax over j (16-lane groups per head).
// Phase C: accumulate o_hat (12x128), o (12x16), o_hp_global (12x8x3);
//          inverse transform + norms; write cat row (2112).
// ---------------------------------------------------------------------------
__global__ __launch_bounds__(256) void k_attn(
    const float* __restrict__ z, const float* __restrict__ rots,
    const float* __restrict__ trans, const float* __restrict__ Wb,
    const float* __restrict__ gamma,
    const float* __restrict__ qh, const float* __restrict__ kh,
    const float* __restrict__ vh, const float* __restrict__ qg,
    const float* __restrict__ kg, const float* __restrict__ vg,
    float* __restrict__ cat)
{
    const int i   = blockIdx.x;
    const int tid = threadIdx.x;
    __shared__ float q_lds[192];
    __shared__ float qg_lds[144];
    __shared__ float wb_lds[CZ * NH];    // 6 KB, [c][h]
    __shared__ float gam_lds[NH];
    __shared__ float l_lds[NRES * NH];   // 24 KB logits -> probs
    __shared__ float ohp_lds[288];

    if (tid < 192) q_lds[tid]  = qh[(size_t)i * 192 + tid];
    if (tid < 144) qg_lds[tid] = qg[(size_t)i * 144 + tid];
    for (int idx = tid; idx < CZ * NH; idx += 256) wb_lds[idx] = Wb[idx];
    if (tid < NH) gam_lds[tid] = gamma[tid];
    __syncthreads();

    // ---- Phase A: logits ----
    const int jl = tid & 63, hg = tid >> 6;   // 4 head-groups of 3 heads
    const int h0 = hg * 3;
    for (int jc = 0; jc < NRES; jc += 64) {
        const int j = jc + jl;
        const float4* zrow = (const float4*)(z + ((size_t)i * NRES + j) * CZ);
        float b0 = 0.f, b1 = 0.f, b2 = 0.f;
        #pragma unroll 8
        for (int c4 = 0; c4 < 32; ++c4) {
            const float4 zv = zrow[c4];
            const float* wb = &wb_lds[c4 * 48 + h0];
            b0 += zv.x * wb[0] + zv.y * wb[12] + zv.z * wb[24] + zv.w * wb[36];
            b1 += zv.x * wb[1] + zv.y * wb[13] + zv.z * wb[25] + zv.w * wb[37];
            b2 += zv.x * wb[2] + zv.y * wb[14] + zv.z * wb[26] + zv.w * wb[38];
        }
        float bb[3] = { b0, b1, b2 };
        #pragma unroll
        for (int h3 = 0; h3 < 3; ++h3) {
            const int h = h0 + h3;
            const float4* kp  = (const float4*)(kh + (size_t)j * 192 + h * 16);
            const float4* qp  = (const float4*)(q_lds + h * 16);
            float as = 0.f;
            #pragma unroll
            for (int u = 0; u < 4; ++u) {
                float4 kv = kp[u], qv = qp[u];
                as += kv.x * qv.x + kv.y * qv.y + kv.z * qv.z + kv.w * qv.w;
            }
            const float4* kgp = (const float4*)(kg + (size_t)j * 144 + h * 12);
            const float4* qgp = (const float4*)(qg_lds + h * 12);
            float d2 = 0.f;
            #pragma unroll
            for (int u = 0; u < 3; ++u) {
                float4 av = qgp[u], bv = kgp[u];
                float dx = av.x - bv.x, dy = av.y - bv.y;
                float dz = av.z - bv.z, dw = av.w - bv.w;
                d2 += dx * dx + dy * dy + dz * dz + dw * dw;
            }
            float logit = WL_F * (as * 0.25f + bb[h3] - HALF_WC_F * gam_lds[h] * d2);
            l_lds[j * NH + h] = logit;
        }
    }
    __syncthreads();

    // ---- Phase B: softmax over j, per head; 16 lanes per head ----
    if (tid < 192) {
        const int h = tid >> 4, s = tid & 15;
        float m = -1e30f;
        for (int j = s; j < NRES; j += 16) m = fmaxf(m, l_lds[j * NH + h]);
        #pragma unroll
        for (int o = 1; o < 16; o <<= 1) m = fmaxf(m, __shfl_xor(m, o));
        float sum = 0.f;
        for (int j = s; j < NRES; j += 16) sum += __expf(l_lds[j * NH + h] - m);
        #pragma unroll
        for (int o = 1; o < 16; o <<= 1) sum += __shfl_xor(sum, o);
        const float inv = 1.0f / sum;
        for (int j = s; j < NRES; j += 16)
            l_lds[j * NH + h] = __expf(l_lds[j * NH + h] - m) * inv;
    }
    __syncthreads();

    // ---- Phase C: weighted accumulation ----
    const int d   = tid & 127;       // z channel
    const int hb  = tid >> 7;        // 0/1 -> heads hb+2k
    const int ho  = tid >> 4;        // o: head (tid<192)
    const int hp0 = tid / 24;        // o_hp elem tid
    const int hp1 = (tid + 256) / 24;
    float ahat[6];
    #pragma unroll
    for (int k = 0; k < 6; ++k) ahat[k] = 0.f;
    float ao = 0.f, ahp0 = 0.f, ahp1 = 0.f;

    for (int j = 0; j < NRES; ++j) {
        const float* pl = &l_lds[j * NH];
        const float zv = z[((size_t)i * NRES + j) * CZ + d];
        #pragma unroll
        for (int k = 0; k < 6; ++k) ahat[k] += pl[hb + 2 * k] * zv;
        if (tid < 192) ao += pl[ho] * vh[(size_t)j * 192 + tid];
        ahp0 += pl[hp0] * vg[(size_t)j * 288 + tid];
        if (tid < 32) ahp1 += pl[hp1] * vg[(size_t)j * 288 + 256 + tid];
    }

    float* crow = cat + (size_t)i * 2112;
    #pragma unroll
    for (int k = 0; k < 6; ++k) crow[(hb + 2 * k) * 128 + d] = ahat[k];
    if (tid < 192) crow[1536 + tid] = ao;
    ohp_lds[tid] = ahp0;
    if (tid < 32) ohp_lds[256 + tid] = ahp1;
    __syncthreads();

    if (tid < 96) {
        const int h = tid >> 3, p = tid & 7;
        float R[9];
        #pragma unroll
        for (int k = 0; k < 9; ++k) R[k] = rots[(size_t)i * 9 + k];
        float g0 = ohp_lds[h * 24 + p * 3 + 0] - trans[(size_t)i * 3 + 0];
        float g1 = ohp_lds[h * 24 + p * 3 + 1] - trans[(size_t)i * 3 + 1];
        float g2 = ohp_lds[h * 24 + p * 3 + 2] - trans[(size_t)i * 3 + 2];
        // inv_apply: out[y] = sum_x R[x,y] * g[x]
        float oy0 = R[0] * g0 + R[3] * g1 + R[6] * g2;
        float oy1 = R[1] * g0 + R[4] * g1 + R[7] * g2;
        float oy2 = R[2] * g0 + R[5] * g1 + R[8] * g2;
        crow[1728 + h * 24 + p * 3 + 0] = oy0;
        crow[1728 + h * 24 + p * 3 + 1] = oy1;
        crow[1728 + h * 24 + p * 3 + 2] = oy2;
        crow[2016 + h * 8 + p] = sqrtf(oy0 * oy0 + oy1 * oy1 + oy2 * oy2);
    }
}

// ---------------------------------------------------------------------------
// Kernel 3: out = cat (512x2112) @ Wout (2112x384) + bout.
// grid (3 col-tiles of 128, 64 row-tiles of 8), 256 threads.
// Each thread: 2 cols x 2 rows.
// ---------------------------------------------------------------------------
__global__ __launch_bounds__(256) void k_out(
    const float* __restrict__ cat, const float* __restrict__ Wout,
    const float* __restrict__ bout, float* __restrict__ out)
{
    const int tid = threadIdx.x;
    const int cp  = tid & 63;
    const int qd  = tid >> 6;            // 0..3
    const int c0  = blockIdx.x * 128 + cp * 2;
    const int i0  = blockIdx.y * 8;
    const int r0  = qd * 2, r1 = r0 + 1;
    __shared__ float lds[8][65];
    float a00, a01, a10, a11;
    a00 = a10 = bout[c0];
    a01 = a11 = bout[c0 + 1];
    for (int kc = 0; kc < 2112; kc += 64) {
        __syncthreads();
        for (int idx = tid; idx < 512; idx += 256) {
            int r = idx >> 6, kk = idx & 63;
            lds[r][kk] = cat[(size_t)(i0 + r) * 2112 + kc + kk];
        }
        __syncthreads();
        #pragma unroll 8
        for (int kk = 0; kk < 64; ++kk) {
            const float2 w = *(const float2*)(Wout + (size_t)(kc + kk) * 384 + c0);
            float l0 = lds[r0][kk], l1 = lds[r1][kk];
            a00 += l0 * w.x; a01 += l0 * w.y;
            a10 += l1 * w.x; a11 += l1 * w.y;
        }
    }
    out[(size_t)(i0 + r0) * 384 + c0]     = a00;
    out[(size_t)(i0 + r0) * 384 + c0 + 1] = a01;
    out[(size_t)(i0 + r1) * 384 + c0]     = a10;
    out[(size_t)(i0 + r1) * 384 + c0 + 1] = a11;
}

// ---------------------------------------------------------------------------
extern "C" void kernel_launch(void* const* d_in, const int* in_sizes, int n_in,
                              void* d_out, int out_size, void* d_ws, size_t ws_size,
                              hipStream_t stream)
{
    const float* s_i   = (const float*)d_in[0];
    const float* z_ij  = (const float*)d_in[1];
    const float* rots  = (const float*)d_in[2];
    const float* trans = (const float*)d_in[3];
    const float* Wq    = (const float*)d_in[4];
    const float* Wk    = (const float*)d_in[5];
    const float* Wv    = (const float*)d_in[6];
    const float* Wqp   = (const float*)d_in[7];
    const float* Wkp   = (const float*)d_in[8];
    const float* Wvp   = (const float*)d_in[9];
    const float* Wb    = (const float*)d_in[10];
    const float* gamma = (const float*)d_in[11];
    const float* Wout  = (const float*)d_in[12];
    const float* bout  = (const float*)d_in[13];
    float* ws  = (float*)d_ws;
    float* qh  = ws;                 // 512*192
    float* kh  = qh + 98304;         // 512*192
    float* vh  = kh + 98304;         // 512*192
    float* qg  = vh + 98304;         // 512*144
    float* kg  = qg + 73728;         // 512*144
    float* vg  = kg + 73728;         // 512*288
    float* cat = vg + 147456;        // 512*2112
    float* out = (float*)d_out;

    hipLaunchKernelGGL(k_proj, dim3(4, 64), dim3(256), 0, stream,
                       s_i, rots, trans, Wq, Wk, Wv, Wqp, Wkp, Wvp,
                       qh, kh, vh, qg, kg, vg);
    hipLaunchKernelGGL(k_attn, dim3(512), dim3(256), 0, stream,
                       z_ij, rots, trans, Wb, gamma,
                       qh, kh, vh, qg, kg, vg, cat);
    hipLaunchKernelGGL(k_out, dim3(3, 64), dim3(256), 0, stream,
                       cat, Wout, bout, out);
}

// Round 2
// 340.530 us; speedup vs baseline: 2.0251x; 2.0251x over previous
//
#include <hip/hip_runtime.h>
#include <hip/hip_bf16.h>
#include <math.h>

#define NRES 512
#define CS   384
#define CZ   128
#define NH   12

static constexpr float WL_F      = 0.57735026918962576f;   // sqrt(1/3)
static constexpr float HALF_WC_F = 0.11785113019775792f;   // 0.5*sqrt(2/(9*4))

// ---------------------------------------------------------------------------
// Kernel 1: projections. grid (6 kinds, 128 i-tiles of 4 rows), 256 threads.
// kinds: 0=q,1=k,2=v (width 192 -> qh/kh/vh), 3=qp,4=kp (144 -> rigid -> qg/kg),
// 5=vp (288 -> rigid -> vg).
// ---------------------------------------------------------------------------
__global__ __launch_bounds__(256) void k_proj(
    const float* __restrict__ s, const float* __restrict__ rots,
    const float* __restrict__ trans,
    const float* __restrict__ Wq, const float* __restrict__ Wk,
    const float* __restrict__ Wv, const float* __restrict__ Wqp,
    const float* __restrict__ Wkp, const float* __restrict__ Wvp,
    float* __restrict__ qh, float* __restrict__ kh, float* __restrict__ vh,
    float* __restrict__ qg, float* __restrict__ kg, float* __restrict__ vg)
{
    const int tid  = threadIdx.x;
    const int kind = blockIdx.x;
    const int i0   = blockIdx.y * 4;
    __shared__ float s_lds[4][CS];       // 6 KB
    __shared__ float hp_lds[4][288];     // 4.6 KB

    for (int idx = tid; idx < 4 * CS; idx += 256) {
        int r = idx / CS, c = idx % CS;
        s_lds[r][c] = s[(size_t)(i0 + r) * CS + c];
    }
    __syncthreads();

    const float* Wsel;
    int W;
    switch (kind) {
        case 0: Wsel = Wq;  W = 192; break;
        case 1: Wsel = Wk;  W = 192; break;
        case 2: Wsel = Wv;  W = 192; break;
        case 3: Wsel = Wqp; W = 144; break;
        case 4: Wsel = Wkp; W = 144; break;
        default: Wsel = Wvp; W = 288; break;
    }

    for (int col = tid; col < W; col += 256) {
        float acc[4] = {0.f, 0.f, 0.f, 0.f};
        #pragma unroll 4
        for (int c = 0; c < CS; ++c) {
            float w = Wsel[(size_t)c * W + col];
            #pragma unroll
            for (int r = 0; r < 4; ++r) acc[r] += s_lds[r][c] * w;
        }
        #pragma unroll
        for (int r = 0; r < 4; ++r) {
            int i = i0 + r;
            if (kind == 0)      qh[(size_t)i * 192 + col] = acc[r];
            else if (kind == 1) kh[(size_t)i * 192 + col] = acc[r];
            else if (kind == 2) vh[(size_t)i * 192 + col] = acc[r];
            else                hp_lds[r][col] = acc[r];
        }
    }
    if (kind < 3) return;
    __syncthreads();

    // rigid transform: out[x] = sum_y R[x,y]*v[y] + t[x]
    const int npts = (kind == 5) ? 384 : 192;   // 4 rows x (96 or 48) points
    const int ppr  = (kind == 5) ? 96 : 48;
    for (int t = tid; t < npts; t += 256) {
        const int r = t / ppr, pt = t % ppr;
        const int i = i0 + r;
        float R[9], T[3];
        #pragma unroll
        for (int k = 0; k < 9; ++k) R[k] = rots[(size_t)i * 9 + k];
        #pragma unroll
        for (int k = 0; k < 3; ++k) T[k] = trans[(size_t)i * 3 + k];
        const float* src = &hp_lds[r][pt * 3];
        float* dst;
        if (kind == 3)      dst = &qg[(size_t)i * 144 + pt * 3];
        else if (kind == 4) dst = &kg[(size_t)i * 144 + pt * 3];
        else                dst = &vg[(size_t)i * 288 + pt * 3];
        float v0 = src[0], v1 = src[1], v2 = src[2];
        #pragma unroll
        for (int x = 0; x < 3; ++x)
            dst[x] = R[x * 3 + 0] * v0 + R[x * 3 + 1] * v1 + R[x * 3 + 2] * v2 + T[x];
    }
}

// ---------------------------------------------------------------------------
// Kernel 2: flash-style attention chunk. grid (512 i, 4 jc), 256 threads.
// Per chunk of 128 j: logits -> chunk softmax (m,s) -> unnormalized partial
// accumulation of o_hat (12x128), o (12x16), o_hp (12x8x3) into ws.
// partial layout (stride 2048): [0,1536) ahat | [1536,1728) ao |
// [1728,2016) ahp | [2016,2028) m | [2028,2040) s
// ---------------------------------------------------------------------------
__global__ __launch_bounds__(256) void k_flash(
    const float* __restrict__ z, const float* __restrict__ Wb,
    const float* __restrict__ gamma,
    const float* __restrict__ qh, const float* __restrict__ kh,
    const float* __restrict__ vh, const float* __restrict__ qg,
    const float* __restrict__ kg, const float* __restrict__ vg,
    float* __restrict__ part)
{
    const int i   = blockIdx.x;
    const int jc  = blockIdx.y;
    const int j0  = jc * 128;
    const int tid = threadIdx.x;

    __shared__ float q_lds[192];
    __shared__ float qg_lds[144];
    __shared__ float wb_lds[CZ * NH];    // 6 KB [c][h]
    __shared__ float gam_lds[NH];
    __shared__ float l_lds[128 * NH];    // 6 KB
    __shared__ float pm[NH], ps[NH];

    if (tid < 192) q_lds[tid]  = qh[(size_t)i * 192 + tid];
    if (tid < 144) qg_lds[tid] = qg[(size_t)i * 144 + tid];
    for (int idx = tid; idx < CZ * NH; idx += 256) wb_lds[idx] = Wb[idx];
    if (tid < NH) gam_lds[tid] = gamma[tid];
    __syncthreads();

    // ---- logits: thread = (jl, p); p-half of z channels, p-half of heads ----
    {
        const int jl = tid >> 1, p = tid & 1;
        const int j  = j0 + jl;
        const float4* zrow = (const float4*)(z + ((size_t)i * NRES + j) * CZ);
        float b[NH];
        #pragma unroll
        for (int h = 0; h < NH; ++h) b[h] = 0.f;
        #pragma unroll 4
        for (int c4 = 0; c4 < 16; ++c4) {
            const float4 zv = zrow[p * 16 + c4];
            const float* wb = &wb_lds[(p * 16 + c4) * 48];
            #pragma unroll
            for (int h = 0; h < NH; ++h)
                b[h] += zv.x * wb[h] + zv.y * wb[12 + h] + zv.z * wb[24 + h] + zv.w * wb[36 + h];
        }
        #pragma unroll
        for (int h = 0; h < NH; ++h) b[h] += __shfl_xor(b[h], 1);

        const int h0 = p * 6;
        #pragma unroll
        for (int h3 = 0; h3 < 6; ++h3) {
            const int h = h0 + h3;
            const float4* kp = (const float4*)(kh + (size_t)j * 192 + h * 16);
            const float4* qp = (const float4*)(q_lds + h * 16);
            float as = 0.f;
            #pragma unroll
            for (int u = 0; u < 4; ++u) {
                float4 kv = kp[u], qv = qp[u];
                as += kv.x * qv.x + kv.y * qv.y + kv.z * qv.z + kv.w * qv.w;
            }
            const float4* kgp = (const float4*)(kg + (size_t)j * 144 + h * 12);
            const float4* qgp = (const float4*)(qg_lds + h * 12);
            float d2 = 0.f;
            #pragma unroll
            for (int u = 0; u < 3; ++u) {
                float4 av = qgp[u], bv = kgp[u];
                float dx = av.x - bv.x, dy = av.y - bv.y;
                float dz = av.z - bv.z, dw = av.w - bv.w;
                d2 += dx * dx + dy * dy + dz * dz + dw * dw;
            }
            l_lds[jl * NH + h] =
                WL_F * (as * 0.25f + b[h] - HALF_WC_F * gam_lds[h] * d2);
        }
    }
    __syncthreads();

    // ---- chunk softmax: 16 lanes per head ----
    if (tid < 192) {
        const int h = tid >> 4, s = tid & 15;
        if (h < NH) {
            float m = -1e30f;
            for (int j = s; j < 128; j += 16) m = fmaxf(m, l_lds[j * NH + h]);
            #pragma unroll
            for (int o = 1; o < 16; o <<= 1) m = fmaxf(m, __shfl_xor(m, o));
            float sum = 0.f;
            for (int j = s; j < 128; j += 16) {
                float e = __expf(l_lds[j * NH + h] - m);
                l_lds[j * NH + h] = e;
                sum += e;
            }
            #pragma unroll
            for (int o = 1; o < 16; o <<= 1) sum += __shfl_xor(sum, o);
            if (s == 0) { pm[h] = m; ps[h] = sum; }
        }
    }
    __syncthreads();

    // ---- unnormalized accumulation over the 128-chunk ----
    const int d   = tid & 127;
    const int hb  = tid >> 7;
    const int ho  = tid >> 4;
    const int hp0 = tid / 24;
    const int hp1 = (tid + 256) / 24;
    float ahat[6] = {0.f, 0.f, 0.f, 0.f, 0.f, 0.f};
    float ao = 0.f, ahp0 = 0.f, ahp1 = 0.f;

    for (int jj = 0; jj < 128; ++jj) {
        const int j = j0 + jj;
        const float* pl = &l_lds[jj * NH];
        const float zv = z[((size_t)i * NRES + j) * CZ + d];
        #pragma unroll
        for (int k = 0; k < 6; ++k) ahat[k] += pl[hb + 2 * k] * zv;
        if (tid < 192) ao += pl[ho] * vh[(size_t)j * 192 + tid];
        ahp0 += pl[hp0] * vg[(size_t)j * 288 + tid];
        if (tid < 32) ahp1 += pl[hp1] * vg[(size_t)j * 288 + 256 + tid];
    }

    float* pb = part + ((size_t)i * 4 + jc) * 2048;
    #pragma unroll
    for (int k = 0; k < 6; ++k) pb[(hb + 2 * k) * 128 + d] = ahat[k];
    if (tid < 192) pb[1536 + tid] = ao;
    pb[1728 + tid] = ahp0;
    if (tid < 32) pb[1728 + 256 + tid] = ahp1;
    if (tid < NH) { pb[2016 + tid] = pm[tid]; pb[2028 + tid] = ps[tid]; }
}

// ---------------------------------------------------------------------------
// Kernel 3: combine 4 chunks -> cat row. grid 512, 256 threads.
// ---------------------------------------------------------------------------
__global__ __launch_bounds__(256) void k_combine(
    const float* __restrict__ part, const float* __restrict__ rots,
    const float* __restrict__ trans, float* __restrict__ cat)
{
    const int i   = blockIdx.x;
    const int tid = threadIdx.x;
    __shared__ float wgt[4][NH];
    __shared__ float ohp[288];

    const float* pb = part + (size_t)i * 4 * 2048;
    if (tid < NH) {
        const int h = tid;
        float m0 = pb[2016 + h], m1 = pb[2048 + 2016 + h];
        float m2 = pb[4096 + 2016 + h], m3 = pb[6144 + 2016 + h];
        float M = fmaxf(fmaxf(m0, m1), fmaxf(m2, m3));
        float w0 = __expf(m0 - M), w1 = __expf(m1 - M);
        float w2 = __expf(m2 - M), w3 = __expf(m3 - M);
        float S = w0 * pb[2028 + h] + w1 * pb[2048 + 2028 + h] +
                  w2 * pb[4096 + 2028 + h] + w3 * pb[6144 + 2028 + h];
        float inv = 1.0f / S;
        wgt[0][h] = w0 * inv; wgt[1][h] = w1 * inv;
        wgt[2][h] = w2 * inv; wgt[3][h] = w3 * inv;
    }
    __syncthreads();

    float* crow = cat + (size_t)i * 2112;
    for (int idx = tid; idx < 1536; idx += 256) {
        const int h = idx >> 7;
        float v = 0.f;
        #pragma unroll
        for (int c = 0; c < 4; ++c) v += pb[c * 2048 + idx] * wgt[c][h];
        crow[idx] = v;
    }
    if (tid < 192) {
        const int h = tid >> 4;
        float v = 0.f;
        #pragma unroll
        for (int c = 0; c < 4; ++c) v += pb[c * 2048 + 1536 + tid] * wgt[c][h];
        crow[1536 + tid] = v;
    }
    for (int e = tid; e < 288; e += 256) {
        const int h = e / 24;
        float v = 0.f;
        #pragma unroll
        for (int c = 0; c < 4; ++c) v += pb[c * 2048 + 1728 + e] * wgt[c][h];
        ohp[e] = v;
    }
    __syncthreads();

    if (tid < 96) {
        const int h = tid >> 3, p = tid & 7;
        float R[9];
        #pragma unroll
        for (int k = 0; k < 9; ++k) R[k] = rots[(size_t)i * 9 + k];
        float g0 = ohp[h * 24 + p * 3 + 0] - trans[(size_t)i * 3 + 0];
        float g1 = ohp[h * 24 + p * 3 + 1] - trans[(size_t)i * 3 + 1];
        float g2 = ohp[h * 24 + p * 3 + 2] - trans[(size_t)i * 3 + 2];
        float oy0 = R[0] * g0 + R[3] * g1 + R[6] * g2;
        float oy1 = R[1] * g0 + R[4] * g1 + R[7] * g2;
        float oy2 = R[2] * g0 + R[5] * g1 + R[8] * g2;
        crow[1728 + h * 24 + p * 3 + 0] = oy0;
        crow[1728 + h * 24 + p * 3 + 1] = oy1;
        crow[1728 + h * 24 + p * 3 + 2] = oy2;
        crow[2016 + h * 8 + p] = sqrtf(oy0 * oy0 + oy1 * oy1 + oy2 * oy2);
    }
}

// ---------------------------------------------------------------------------
// Kernel 4: out-proj partials. grid (3 ctile, 64 rtile, 3 ksplit of 704).
// ---------------------------------------------------------------------------
__global__ __launch_bounds__(256) void k_out(
    const float* __restrict__ cat, const float* __restrict__ Wout,
    float* __restrict__ opart)
{
    const int tid = threadIdx.x;
    const int cp  = tid & 63;
    const int qd  = tid >> 6;
    const int c0  = blockIdx.x * 128 + cp * 2;
    const int i0  = blockIdx.y * 8;
    const int k0  = blockIdx.z * 704;
    const int r0  = qd * 2, r1 = r0 + 1;
    __shared__ float lds[8][65];
    float a00 = 0.f, a01 = 0.f, a10 = 0.f, a11 = 0.f;
    for (int kc = k0; kc < k0 + 704; kc += 64) {
        __syncthreads();
        for (int idx = tid; idx < 512; idx += 256) {
            int r = idx >> 6, kk = idx & 63;
            lds[r][kk] = cat[(size_t)(i0 + r) * 2112 + kc + kk];
        }
        __syncthreads();
        #pragma unroll 8
        for (int kk = 0; kk < 64; ++kk) {
            const float2 w = *(const float2*)(Wout + (size_t)(kc + kk) * 384 + c0);
            float l0 = lds[r0][kk], l1 = lds[r1][kk];
            a00 += l0 * w.x; a01 += l0 * w.y;
            a10 += l1 * w.x; a11 += l1 * w.y;
        }
    }
    float* ob = opart + (size_t)blockIdx.z * 512 * 384;
    ob[(size_t)(i0 + r0) * 384 + c0]     = a00;
    ob[(size_t)(i0 + r0) * 384 + c0 + 1] = a01;
    ob[(size_t)(i0 + r1) * 384 + c0]     = a10;
    ob[(size_t)(i0 + r1) * 384 + c0 + 1] = a11;
}

// Kernel 5: reduce 3 k-partials + bias. grid 192 x 256, float4 per thread.
__global__ __launch_bounds__(256) void k_outred(
    const float* __restrict__ opart, const float* __restrict__ bout,
    float* __restrict__ out)
{
    const int e4 = blockIdx.x * 256 + threadIdx.x;   // [0, 49152)
    const float4* p = (const float4*)opart;
    const float4 b = ((const float4*)bout)[e4 % 96];
    float4 v0 = p[e4], v1 = p[e4 + 49152], v2 = p[e4 + 98304];
    float4 r;
    r.x = v0.x + v1.x + v2.x + b.x;
    r.y = v0.y + v1.y + v2.y + b.y;
    r.z = v0.z + v1.z + v2.z + b.z;
    r.w = v0.w + v1.w + v2.w + b.w;
    ((float4*)out)[e4] = r;
}

// ---------------------------------------------------------------------------
extern "C" void kernel_launch(void* const* d_in, const int* in_sizes, int n_in,
                              void* d_out, int out_size, void* d_ws, size_t ws_size,
                              hipStream_t stream)
{
    const float* s_i   = (const float*)d_in[0];
    const float* z_ij  = (const float*)d_in[1];
    const float* rots  = (const float*)d_in[2];
    const float* trans = (const float*)d_in[3];
    const float* Wq    = (const float*)d_in[4];
    const float* Wk    = (const float*)d_in[5];
    const float* Wv    = (const float*)d_in[6];
    const float* Wqp   = (const float*)d_in[7];
    const float* Wkp   = (const float*)d_in[8];
    const float* Wvp   = (const float*)d_in[9];
    const float* Wb    = (const float*)d_in[10];
    const float* gamma = (const float*)d_in[11];
    const float* Wout  = (const float*)d_in[12];
    const float* bout  = (const float*)d_in[13];
    float* ws    = (float*)d_ws;
    float* qh    = ws;                  // 512*192
    float* kh    = qh + 98304;
    float* vh    = kh + 98304;
    float* qg    = vh + 98304;          // 512*144
    float* kg    = qg + 73728;
    float* vg    = kg + 73728;          // 512*288
    float* part  = vg + 147456;         // 512*4*2048
    float* cat   = part + 4194304;      // 512*2112
    float* opart = cat + 1081344;       // 3*512*384
    float* out   = (float*)d_out;

    hipLaunchKernelGGL(k_proj, dim3(6, 128), dim3(256), 0, stream,
                       s_i, rots, trans, Wq, Wk, Wv, Wqp, Wkp, Wvp,
                       qh, kh, vh, qg, kg, vg);
    hipLaunchKernelGGL(k_flash, dim3(512, 4), dim3(256), 0, stream,
                       z_ij, Wb, gamma, qh, kh, vh, qg, kg, vg, part);
    hipLaunchKernelGGL(k_combine, dim3(512), dim3(256), 0, stream,
                       part, rots, trans, cat);
    hipLaunchKernelGGL(k_out, dim3(3, 64, 3), dim3(256), 0, stream,
                       cat, Wout, opart);
    hipLaunchKernelGGL(k_outred, dim3(192), dim3(256), 0, stream,
                       opart, bout, out);
}